// Round 9
// baseline (199.616 us; speedup 1.0000x reference)
//
#include <hip/hip_runtime.h>
#include <hip/hip_bf16.h>

#define SEQ   2048
#define EMB   1024
#define NHEAD 16
#define DHEAD 64
#define BATCH 2
#define MTOT  (BATCH*SEQ)   // 4096
#define QT    128           // queries per attention block
#define KT    64            // keys per tile

typedef __attribute__((ext_vector_type(8))) short s8v;   // 8 bf16 (4 VGPRs)
typedef __attribute__((ext_vector_type(4))) short s4v;   // 4 bf16 (8 B)
typedef __attribute__((ext_vector_type(4))) float f4v;   // mfma accum

__device__ __forceinline__ float b2f(short s) {
    union { unsigned u; float f; } v;
    v.u = ((unsigned)(unsigned short)s) << 16;
    return v.f;
}
__device__ __forceinline__ short f2b(float f) {
    union { float fl; unsigned u; } v; v.fl = f;
    unsigned u = v.u;
    u = (u + 0x7fffu + ((u >> 16) & 1u)) >> 16;   // round-to-nearest-even
    return (short)u;
}
// packed fp32x2 -> bf16x2 (v_cvt_pk_bf16_f32). Used ONLY where the rounded
// values also feed the softmax denominator (consistency => mode-agnostic).
__device__ __forceinline__ unsigned pk2(float a, float b) {
    union { __hip_bfloat162 h; unsigned u; } c;
    c.h = __float22bfloat162_rn(float2{a, b});
    return c.u;
}
__device__ __forceinline__ float b2f_lo(unsigned u) {
    union { unsigned x; float f; } v; v.x = u << 16; return v.f;
}
__device__ __forceinline__ float b2f_hi(unsigned u) {
    union { unsigned x; float f; } v; v.x = u & 0xffff0000u; return v.f;
}

// Raw workgroup barrier: LDS-visibility only (lgkmcnt drain), does NOT drain
// vmcnt — outstanding global prefetch loads stay in flight across it.
__device__ __forceinline__ void bar_lds() {
    asm volatile("s_waitcnt lgkmcnt(0)\n\ts_barrier" ::: "memory");
}

// ---- fp32 -> bf16 bulk convert: x, Wq, Wk, Wv, Wo ----
__global__ __launch_bounds__(256)
void cvt_bf16(const float* __restrict__ s0, const float* __restrict__ s1,
              const float* __restrict__ s2, const float* __restrict__ s3,
              const float* __restrict__ s4,
              short* __restrict__ d0, short* __restrict__ d1,
              short* __restrict__ d2, short* __restrict__ d3,
              short* __restrict__ d4)
{
    const int seg = blockIdx.y;
    const float* s = seg == 0 ? s0 : seg == 1 ? s1 : seg == 2 ? s2 : seg == 3 ? s3 : s4;
    short*       d = seg == 0 ? d0 : seg == 1 ? d1 : seg == 2 ? d2 : seg == 3 ? d3 : d4;
    const int n4 = (seg == 0 ? MTOT * EMB : EMB * EMB) / 4;
    const int stride = gridDim.x * 256;
    for (int i = blockIdx.x * 256 + threadIdx.x; i < n4; i += stride) {
        const float4 v = ((const float4*)s)[i];
        s4v o;
        o[0] = f2b(v.x); o[1] = f2b(v.y); o[2] = f2b(v.z); o[3] = f2b(v.w);
        ((s4v*)d)[i] = o;
    }
}

// Pipelined NT GEMM (r7, proven): C = A*W^T + bias, bf16 staging.
// K-loop: prefetch tile k+1 into VGPRs during MFMA of tile k; raw barriers
// keep global loads in flight across the sync.
template<int NT, bool FUSED3>
__global__ __launch_bounds__(256, 3)
void gemm_bb2(const short* __restrict__ A,
              const short* __restrict__ W0, const short* __restrict__ W1, const short* __restrict__ W2,
              const float* __restrict__ B0, const float* __restrict__ B1, const float* __restrict__ B2,
              void* __restrict__ C0, void* __restrict__ C1, void* __restrict__ C2)
{
    constexpr int JN = NT / 32;
    constexpr int WP = NT / 32;
    const int K = EMB, N = EMB;
    const int ntiles = EMB / NT;
    const int mat = blockIdx.x / ntiles;
    const int n0  = (blockIdx.x % ntiles) * NT;
    const int m0  = blockIdx.y * 128;
    const short* W  = (mat == 0) ? W0 : (mat == 1 ? W1 : W2);
    const float* Bi = (mat == 0) ? B0 : (mat == 1 ? B1 : B2);
    void*        C  = (mat == 0) ? C0 : (mat == 1 ? C1 : C2);

    __shared__ __align__(16) short As[128 * 72];
    __shared__ __align__(16) short Ws[NT * 72];

    const int tid  = threadIdx.x;
    const int lane = tid & 63;
    const int wave = tid >> 6;
    const int quad = lane >> 4;
    const int l16  = lane & 15;
    const int wm   = wave >> 1;
    const int wn   = wave & 1;

    f4v acc[4][JN] = {};

    const int c = tid & 7;
    const int r = tid >> 3;

    s8v ra[4], rw[WP];
    #pragma unroll
    for (int p = 0; p < 4; ++p)
        ra[p] = *(const s8v*)(A + (size_t)(m0 + r + p * 32) * K + c * 8);
    #pragma unroll
    for (int p = 0; p < WP; ++p)
        rw[p] = *(const s8v*)(W + (size_t)(n0 + r + p * 32) * K + c * 8);

    for (int k0 = 0; k0 < K; k0 += 64) {
        if (k0) bar_lds();
        #pragma unroll
        for (int p = 0; p < 4; ++p)
            *(s8v*)(As + (r + p * 32) * 72 + c * 8) = ra[p];
        #pragma unroll
        for (int p = 0; p < WP; ++p)
            *(s8v*)(Ws + (r + p * 32) * 72 + c * 8) = rw[p];
        if (k0 + 64 < K) {
            #pragma unroll
            for (int p = 0; p < 4; ++p)
                ra[p] = *(const s8v*)(A + (size_t)(m0 + r + p * 32) * K + k0 + 64 + c * 8);
            #pragma unroll
            for (int p = 0; p < WP; ++p)
                rw[p] = *(const s8v*)(W + (size_t)(n0 + r + p * 32) * K + k0 + 64 + c * 8);
        }
        bar_lds();

        #pragma unroll
        for (int kk = 0; kk < 2; ++kk) {
            const int ko = kk * 32 + quad * 8;
            s8v af[4], wf[JN];
            #pragma unroll
            for (int i = 0; i < 4; ++i)
                af[i] = *(const s8v*)(As + (wm * 64 + i * 16 + l16) * 72 + ko);
            #pragma unroll
            for (int j = 0; j < JN; ++j)
                wf[j] = *(const s8v*)(Ws + (wn * (NT / 2) + j * 16 + l16) * 72 + ko);
            #pragma unroll
            for (int i = 0; i < 4; ++i)
                #pragma unroll
                for (int j = 0; j < JN; ++j)
                    acc[i][j] = __builtin_amdgcn_mfma_f32_16x16x32_bf16(
                        af[i], wf[j], acc[i][j], 0, 0, 0);
        }
    }

    #pragma unroll
    for (int j = 0; j < JN; ++j) {
        const int n = n0 + wn * (NT / 2) + j * 16 + l16;
        const float bv = Bi[n];
        #pragma unroll
        for (int i = 0; i < 4; ++i) {
            const int mb = m0 + wm * 64 + i * 16 + quad * 4;
            if (FUSED3 && mat == 2) {
                const int bb = mb >> 11, s = mb & 2047;
                s4v ov;
                #pragma unroll
                for (int rr = 0; rr < 4; ++rr) ov[rr] = f2b(acc[i][j][rr] + bv);
                *(s4v*)((short*)C + ((size_t)(bb * 1024 + n)) * SEQ + s) = ov;
            } else if (FUSED3) {
                #pragma unroll
                for (int rr = 0; rr < 4; ++rr)
                    ((short*)C)[(size_t)(mb + rr) * N + n] = f2b(acc[i][j][rr] + bv);
            } else {
                #pragma unroll
                for (int rr = 0; rr < 4; ++rr)
                    ((float*)C)[(size_t)(mb + rr) * N + n] = acc[i][j][rr] + bv;
            }
        }
    }
}

// MFMA flash attention v4 (r7, empirically deterministic) + consistency fix:
// lsum is now summed from the bf16-ROUNDED P values that feed the PV MFMA,
// so softmax P-rounding cancels to first order in the num/denom ratio.
// Double-buffered Ks/Vs + VGPR prefetch one tile ahead + raw barriers:
// ONE barrier per tile, global-load latency hidden under compute.
// S^T = mfma(K,Q) so P packs along keys (s4v); P rows wave-private.
// V arrives pre-transposed [b][h][d][s]. O aliases Q (own 128 rows x own
// head's 64 cols only; Q read into regs first).
__global__ __launch_bounds__(256, 2)
void attn_mfma4(const short* Q, const short* __restrict__ Kg,
                const short* __restrict__ Vt, short* O)
{
    const int blk = blockIdx.x;     // 512
    const int qb = blk & 15;
    const int h  = (blk >> 4) & 15;
    const int b  = blk >> 8;
    const int q0 = qb * QT;

    const int tid  = threadIdx.x;
    const int lane = tid & 63;
    const int wave = tid >> 6;
    const int quad = lane >> 4;
    const int l16  = lane & 15;

    __shared__ __align__(16) short Ks[2][64 * 72];   // [key][d]
    __shared__ __align__(16) short Vs[2][64 * 72];   // [d][key]
    __shared__ __align__(16) short Pt[QT * 72];      // [q][key], wave-private

    // Q B-frags for the whole kernel: [mi][kk]
    s8v qf[2][2];
    #pragma unroll
    for (int mi = 0; mi < 2; ++mi)
        #pragma unroll
        for (int kk = 0; kk < 2; ++kk)
            qf[mi][kk] = *(const s8v*)(Q + (size_t)(b * SEQ + q0 + wave * 32 + mi * 16 + l16) * EMB
                                         + h * DHEAD + kk * 32 + quad * 8);

    f4v   oacc[4][2] = {};   // [j: d-block][mi] -> O^T[d][q]
    float lsum[2] = {};      // per-lane partial sums (of ROUNDED p)

    const int c = tid & 7, r = tid >> 3;
    const size_t kbase = (size_t)(b * SEQ) * EMB + h * DHEAD;
    const size_t vbase = (size_t)((b * NHEAD + h) * DHEAD) * SEQ;

    // prologue: prefetch tile 0
    s8v ka[2], va[2];
    #pragma unroll
    for (int p = 0; p < 2; ++p) {
        ka[p] = *(const s8v*)(Kg + kbase + (size_t)(r + p * 32) * EMB + c * 8);
        va[p] = *(const s8v*)(Vt + vbase + (size_t)(r + p * 32) * SEQ + c * 8);
    }

    for (int t = 0; t < SEQ / KT; ++t) {
        const int buf = t & 1;
        short* KsB = Ks[buf];
        short* VsB = Vs[buf];

        // write current tile from regs (vmcnt wait only on these regs)
        #pragma unroll
        for (int p = 0; p < 2; ++p) {
            *(s8v*)(KsB + (r + p * 32) * 72 + c * 8) = ka[p];
            *(s8v*)(VsB + (r + p * 32) * 72 + c * 8) = va[p];
        }
        // async prefetch of next tile (stays in flight across the barrier)
        if (t + 1 < SEQ / KT) {
            const int kt2 = (t + 1) * KT;
            #pragma unroll
            for (int p = 0; p < 2; ++p) {
                ka[p] = *(const s8v*)(Kg + kbase + (size_t)(kt2 + r + p * 32) * EMB + c * 8);
                va[p] = *(const s8v*)(Vt + vbase + (size_t)(r + p * 32) * SEQ + kt2 + c * 8);
            }
        }
        bar_lds();   // tile visible; prefetch NOT drained

        // ---- S^T[key][q] = K · Q^T ----
        f4v sc[4][2] = {};
        #pragma unroll
        for (int kk = 0; kk < 2; ++kk) {
            const int ko = kk * 32 + quad * 8;
            s8v kf[4];
            #pragma unroll
            for (int j = 0; j < 4; ++j)
                kf[j] = *(const s8v*)(KsB + (j * 16 + l16) * 72 + ko);
            #pragma unroll
            for (int j = 0; j < 4; ++j)
                #pragma unroll
                for (int mi = 0; mi < 2; ++mi)
                    sc[j][mi] = __builtin_amdgcn_mfma_f32_16x16x32_bf16(
                        kf[j], qf[mi][kk], sc[j][mi], 0, 0, 0);
        }

        // ---- p = exp(s/8), pack to bf16, accumulate ROUNDED p into lsum ----
        // C layout: col=l16=q, row=quad*4+rr=key (within j*16)
        #pragma unroll
        for (int j = 0; j < 4; ++j)
            #pragma unroll
            for (int mi = 0; mi < 2; ++mi) {
                const float p0 = __expf(sc[j][mi][0] * 0.125f);
                const float p1 = __expf(sc[j][mi][1] * 0.125f);
                const float p2 = __expf(sc[j][mi][2] * 0.125f);
                const float p3 = __expf(sc[j][mi][3] * 0.125f);
                union { unsigned u[2]; s4v s; } pv;
                pv.u[0] = pk2(p0, p1);
                pv.u[1] = pk2(p2, p3);
                lsum[mi] += (b2f_lo(pv.u[0]) + b2f_hi(pv.u[0]))
                          + (b2f_lo(pv.u[1]) + b2f_hi(pv.u[1]));
                *(s4v*)(Pt + (wave * 32 + mi * 16 + l16) * 72 + j * 16 + quad * 4) = pv.s;
            }

        // ---- O^T[d][q] += V^T[d][key] · P^T: A=Vs rows, B=Pt rows ----
        #pragma unroll
        for (int kk = 0; kk < 2; ++kk) {
            const int ko = kk * 32 + quad * 8;
            s8v pf[2];
            #pragma unroll
            for (int mi = 0; mi < 2; ++mi)
                pf[mi] = *(const s8v*)(Pt + (wave * 32 + mi * 16 + l16) * 72 + ko);
            #pragma unroll
            for (int j = 0; j < 4; ++j) {
                const s8v vf = *(const s8v*)(VsB + (j * 16 + l16) * 72 + ko);
                #pragma unroll
                for (int mi = 0; mi < 2; ++mi)
                    oacc[j][mi] = __builtin_amdgcn_mfma_f32_16x16x32_bf16(
                        vf, pf[mi], oacc[j][mi], 0, 0, 0);
            }
        }
    }

    // ---- full row sums: butterfly across quads (lane bits 4,5) ----
    #pragma unroll
    for (int mi = 0; mi < 2; ++mi) {
        float s = lsum[mi];
        s += __shfl_xor(s, 16);
        s += __shfl_xor(s, 32);
        lsum[mi] = 1.0f / s;
    }

    // ---- O^T C-layout -> LDS [q][d] packed (reuse Pt; wave-private) ----
    #pragma unroll
    for (int j = 0; j < 4; ++j)
        #pragma unroll
        for (int mi = 0; mi < 2; ++mi) {
            union { unsigned u[2]; s4v s; } ov;
            ov.u[0] = pk2(oacc[j][mi][0] * lsum[mi], oacc[j][mi][1] * lsum[mi]);
            ov.u[1] = pk2(oacc[j][mi][2] * lsum[mi], oacc[j][mi][3] * lsum[mi]);
            *(s4v*)(Pt + (wave * 32 + mi * 16 + l16) * 72 + j * 16 + quad * 4) = ov.s;
        }

    // ---- coalesced store (rows tid>>1 stay within own wave's Pt rows) ----
    const int row = tid >> 1;
    const int off = (tid & 1) * 32;
    #pragma unroll
    for (int c4 = 0; c4 < 4; ++c4) {
        const s8v t = *(const s8v*)(Pt + row * 72 + off + c4 * 8);
        *(s8v*)(O + (size_t)(b * SEQ + q0 + row) * EMB + h * DHEAD + off + c4 * 8) = t;
    }
}

extern "C" void kernel_launch(void* const* d_in, const int* in_sizes, int n_in,
                              void* d_out, int out_size, void* d_ws, size_t ws_size,
                              hipStream_t stream)
{
    const float* x  = (const float*)d_in[0];
    const float* Wq = (const float*)d_in[1];
    const float* bq = (const float*)d_in[2];
    const float* Wk = (const float*)d_in[3];
    const float* bk = (const float*)d_in[4];
    const float* Wv = (const float*)d_in[5];
    const float* bv = (const float*)d_in[6];
    const float* Wo = (const float*)d_in[7];
    const float* bo = (const float*)d_in[8];
    float* out = (float*)d_out;   // fp32 output

    short* xb  = (short*)d_ws;                       // 4096x1024 bf16
    short* Wqb = xb  + (size_t)MTOT * EMB;
    short* Wkb = Wqb + (size_t)EMB * EMB;
    short* Wvb = Wkb + (size_t)EMB * EMB;
    short* Wob = Wvb + (size_t)EMB * EMB;
    short* Qw  = Wob + (size_t)EMB * EMB;            // [token][1024]
    short* Kw  = Qw  + (size_t)MTOT * EMB;           // [token][1024]
    short* Vtw = Kw  + (size_t)MTOT * EMB;           // [b][h][d][s]

    cvt_bf16<<<dim3(1024, 5), 256, 0, stream>>>(x, Wq, Wk, Wv, Wo,
                                                xb, Wqb, Wkb, Wvb, Wob);

    gemm_bb2<128, true><<<dim3(24, 32), 256, 0, stream>>>(
        xb, Wqb, Wkb, Wvb, bq, bk, bv, Qw, Kw, Vtw);

    attn_mfma4<<<dim3(BATCH * NHEAD * (SEQ / QT)), 256, 0, stream>>>(Qw, Kw, Vtw, Qw);

    gemm_bb2<64, false><<<dim3(16, 32), 256, 0, stream>>>(
        Qw, Wob, Wob, Wob, bo, bo, bo, out, out, out);
}

// Round 10
// 194.687 us; speedup vs baseline: 1.0253x; 1.0253x over previous
//
#include <hip/hip_runtime.h>
#include <hip/hip_bf16.h>

#define SEQ   2048
#define EMB   1024
#define NHEAD 16
#define DHEAD 64
#define BATCH 2
#define MTOT  (BATCH*SEQ)   // 4096
#define QT    128           // queries per attention block
#define KT    64            // keys per tile

typedef __attribute__((ext_vector_type(8))) short s8v;   // 8 bf16 (4 VGPRs)
typedef __attribute__((ext_vector_type(4))) short s4v;   // 4 bf16 (8 B)
typedef __attribute__((ext_vector_type(4))) float f4v;   // mfma accum

__device__ __forceinline__ float b2f(short s) {
    union { unsigned u; float f; } v;
    v.u = ((unsigned)(unsigned short)s) << 16;
    return v.f;
}
__device__ __forceinline__ short f2b(float f) {
    union { float fl; unsigned u; } v; v.fl = f;
    unsigned u = v.u;
    u = (u + 0x7fffu + ((u >> 16) & 1u)) >> 16;   // round-to-nearest-even
    return (short)u;
}
// packed fp32x2 -> bf16x2 (v_cvt_pk_bf16_f32); rounded values also feed the
// softmax denominator (consistency => rounding-mode-agnostic).
__device__ __forceinline__ unsigned pk2(float a, float b) {
    union { __hip_bfloat162 h; unsigned u; } c;
    c.h = __float22bfloat162_rn(float2{a, b});
    return c.u;
}
__device__ __forceinline__ float b2f_lo(unsigned u) {
    union { unsigned x; float f; } v; v.x = u << 16; return v.f;
}
__device__ __forceinline__ float b2f_hi(unsigned u) {
    union { unsigned x; float f; } v; v.x = u & 0xffff0000u; return v.f;
}

// Raw workgroup barrier: LDS-visibility only (lgkmcnt drain), does NOT drain
// vmcnt — outstanding global prefetch loads stay in flight across it.
__device__ __forceinline__ void bar_lds() {
    asm volatile("s_waitcnt lgkmcnt(0)\n\ts_barrier" ::: "memory");
}

// async global->LDS DMA, 16 B/lane; LDS dest = wave-uniform base + lane*16.
__device__ __forceinline__ void gl_lds16(const short* g, short* l) {
    __builtin_amdgcn_global_load_lds(
        (const __attribute__((address_space(1))) void*)g,
        (__attribute__((address_space(3))) void*)l, 16, 0, 0);
}

// ---- fp32 -> bf16 convert + chunk swizzle ----
// Output rows are 1024 bf16 = 16 aligned 128B groups of 8 16B-chunks.
// Chunk c of row r is stored at slot (c&~7) | ((c&7) ^ (r&7)) so that
// global_load_lds' contiguous DMA lands a bank-uniform LDS image.
__global__ __launch_bounds__(256)
void cvt_swz(const float* __restrict__ s0, const float* __restrict__ s1,
             const float* __restrict__ s2, const float* __restrict__ s3,
             const float* __restrict__ s4,
             short* __restrict__ d0, short* __restrict__ d1,
             short* __restrict__ d2, short* __restrict__ d3,
             short* __restrict__ d4)
{
    const int seg = blockIdx.y;
    const float* s = seg == 0 ? s0 : seg == 1 ? s1 : seg == 2 ? s2 : seg == 3 ? s3 : s4;
    short*       d = seg == 0 ? d0 : seg == 1 ? d1 : seg == 2 ? d2 : seg == 3 ? d3 : d4;
    const int nchunk = (seg == 0 ? MTOT * EMB : EMB * EMB) / 8;   // 16B chunks
    const int stride = gridDim.x * 256;
    for (int i = blockIdx.x * 256 + threadIdx.x; i < nchunk; i += stride) {
        const int row = i >> 7;         // 128 chunks per 1024-col row
        const int c   = i & 127;
        const float4 v0 = *(const float4*)(s + (size_t)i * 8);
        const float4 v1 = *(const float4*)(s + (size_t)i * 8 + 4);
        s8v o;
        o[0] = f2b(v0.x); o[1] = f2b(v0.y); o[2] = f2b(v0.z); o[3] = f2b(v0.w);
        o[4] = f2b(v1.x); o[5] = f2b(v1.y); o[6] = f2b(v1.z); o[7] = f2b(v1.w);
        const int cp = (c & ~7) | ((c & 7) ^ (row & 7));
        *(s8v*)(d + (size_t)row * EMB + cp * 8) = o;
    }
}

// NT GEMM via global_load_lds (m97 structure): C = A*W^T + bias.
// A, W are bf16 with swizzled 16B chunks (see cvt_swz). LDS rows unpadded
// (128 B); frag reads address slot (kk*4+quad)^(l16&7) -> bank-uniform.
// FUSED3: 3 matrices (QKV); mat 2 writes V transposed per-head [b][h][d][s].
template<int NT, bool FUSED3>
__global__ __launch_bounds__(256, 3)
void gemm_bb3(const short* __restrict__ A,
              const short* __restrict__ W0, const short* __restrict__ W1, const short* __restrict__ W2,
              const float* __restrict__ B0, const float* __restrict__ B1, const float* __restrict__ B2,
              void* __restrict__ C0, void* __restrict__ C1, void* __restrict__ C2)
{
    constexpr int JN = NT / 32;
    const int K = EMB, N = EMB;
    const int ntiles = EMB / NT;
    const int mat = blockIdx.x / ntiles;
    const int n0  = (blockIdx.x % ntiles) * NT;
    const int m0  = blockIdx.y * 128;
    const short* W  = (mat == 0) ? W0 : (mat == 1 ? W1 : W2);
    const float* Bi = (mat == 0) ? B0 : (mat == 1 ? B1 : B2);
    void*        C  = (mat == 0) ? C0 : (mat == 1 ? C1 : C2);

    __shared__ __align__(16) short As[128 * 64];
    __shared__ __align__(16) short Ws[NT * 64];

    const int tid  = threadIdx.x;
    const int lane = tid & 63;
    const int wave = tid >> 6;
    const int quad = lane >> 4;
    const int l16  = lane & 15;
    const int l8   = l16 & 7;
    const int wm   = wave >> 1;
    const int wn   = wave & 1;

    f4v acc[4][JN] = {};

    const int srow = lane >> 3;    // staging row within 8-row group
    const int scol = (lane & 7) * 8;

    for (int k0 = 0; k0 < K; k0 += 64) {
        // ---- async DMA staging: A rows wave*32.., W rows wave*(NT/4).. ----
        #pragma unroll
        for (int p = 0; p < 4; ++p) {
            const int rbase = wave * 32 + p * 8;
            gl_lds16(A + (size_t)(m0 + rbase + srow) * K + k0 + scol,
                     As + rbase * 64);
        }
        #pragma unroll
        for (int p = 0; p < NT / 32; ++p) {
            const int rbase = wave * (NT / 4) + p * 8;
            gl_lds16(W + (size_t)(n0 + rbase + srow) * K + k0 + scol,
                     Ws + rbase * 64);
        }
        __syncthreads();   // drains the DMA (vmcnt) + barrier

        #pragma unroll
        for (int kk = 0; kk < 2; ++kk) {
            const int slot = ((kk * 4 + quad) ^ l8) * 8;
            s8v af[4], wf[JN];
            #pragma unroll
            for (int i = 0; i < 4; ++i)
                af[i] = *(const s8v*)(As + (wm * 64 + i * 16 + l16) * 64 + slot);
            #pragma unroll
            for (int j = 0; j < JN; ++j)
                wf[j] = *(const s8v*)(Ws + (wn * (NT / 2) + j * 16 + l16) * 64 + slot);
            #pragma unroll
            for (int i = 0; i < 4; ++i)
                #pragma unroll
                for (int j = 0; j < JN; ++j)
                    acc[i][j] = __builtin_amdgcn_mfma_f32_16x16x32_bf16(
                        af[i], wf[j], acc[i][j], 0, 0, 0);
        }
        __syncthreads();   // all waves done reading before next overwrite
    }

    // C/D layout: col = lane&15 (n), row = quad*4+reg (m)   [m89-verified]
    #pragma unroll
    for (int j = 0; j < JN; ++j) {
        const int n = n0 + wn * (NT / 2) + j * 16 + l16;
        const float bv = Bi[n];
        #pragma unroll
        for (int i = 0; i < 4; ++i) {
            const int mb = m0 + wm * 64 + i * 16 + quad * 4;
            if (FUSED3 && mat == 2) {
                const int bb = mb >> 11, s = mb & 2047;
                s4v ov;
                #pragma unroll
                for (int rr = 0; rr < 4; ++rr) ov[rr] = f2b(acc[i][j][rr] + bv);
                *(s4v*)((short*)C + ((size_t)(bb * 1024 + n)) * SEQ + s) = ov;
            } else if (FUSED3) {
                #pragma unroll
                for (int rr = 0; rr < 4; ++rr)
                    ((short*)C)[(size_t)(mb + rr) * N + n] = f2b(acc[i][j][rr] + bv);
            } else {
                #pragma unroll
                for (int rr = 0; rr < 4; ++rr)
                    ((float*)C)[(size_t)(mb + rr) * N + n] = acc[i][j][rr] + bv;
            }
        }
    }
}

// MFMA flash attention v4 (r9, proven deterministic). Only change vs r9:
// the final O store swizzles 16B chunks within each head's 128B group
// (chunk c -> c ^ (row&7)) so the out-projection can stage O via
// global_load_lds. Inputs Q/K/V are read unswizzled as before.
__global__ __launch_bounds__(256, 2)
void attn_mfma4(const short* Q, const short* __restrict__ Kg,
                const short* __restrict__ Vt, short* O)
{
    const int blk = blockIdx.x;     // 512
    const int qb = blk & 15;
    const int h  = (blk >> 4) & 15;
    const int b  = blk >> 8;
    const int q0 = qb * QT;

    const int tid  = threadIdx.x;
    const int lane = tid & 63;
    const int wave = tid >> 6;
    const int quad = lane >> 4;
    const int l16  = lane & 15;

    __shared__ __align__(16) short Ks[2][64 * 72];   // [key][d]
    __shared__ __align__(16) short Vs[2][64 * 72];   // [d][key]
    __shared__ __align__(16) short Pt[QT * 72];      // [q][key], wave-private

    // Q B-frags for the whole kernel: [mi][kk]
    s8v qf[2][2];
    #pragma unroll
    for (int mi = 0; mi < 2; ++mi)
        #pragma unroll
        for (int kk = 0; kk < 2; ++kk)
            qf[mi][kk] = *(const s8v*)(Q + (size_t)(b * SEQ + q0 + wave * 32 + mi * 16 + l16) * EMB
                                         + h * DHEAD + kk * 32 + quad * 8);

    f4v   oacc[4][2] = {};   // [j: d-block][mi] -> O^T[d][q]
    float lsum[2] = {};      // per-lane partial sums (of ROUNDED p)

    const int c = tid & 7, r = tid >> 3;
    const size_t kbase = (size_t)(b * SEQ) * EMB + h * DHEAD;
    const size_t vbase = (size_t)((b * NHEAD + h) * DHEAD) * SEQ;

    // prologue: prefetch tile 0
    s8v ka[2], va[2];
    #pragma unroll
    for (int p = 0; p < 2; ++p) {
        ka[p] = *(const s8v*)(Kg + kbase + (size_t)(r + p * 32) * EMB + c * 8);
        va[p] = *(const s8v*)(Vt + vbase + (size_t)(r + p * 32) * SEQ + c * 8);
    }

    for (int t = 0; t < SEQ / KT; ++t) {
        const int buf = t & 1;
        short* KsB = Ks[buf];
        short* VsB = Vs[buf];

        // write current tile from regs (vmcnt wait only on these regs)
        #pragma unroll
        for (int p = 0; p < 2; ++p) {
            *(s8v*)(KsB + (r + p * 32) * 72 + c * 8) = ka[p];
            *(s8v*)(VsB + (r + p * 32) * 72 + c * 8) = va[p];
        }
        // async prefetch of next tile (stays in flight across the barrier)
        if (t + 1 < SEQ / KT) {
            const int kt2 = (t + 1) * KT;
            #pragma unroll
            for (int p = 0; p < 2; ++p) {
                ka[p] = *(const s8v*)(Kg + kbase + (size_t)(kt2 + r + p * 32) * EMB + c * 8);
                va[p] = *(const s8v*)(Vt + vbase + (size_t)(r + p * 32) * SEQ + kt2 + c * 8);
            }
        }
        bar_lds();   // tile visible; prefetch NOT drained

        // ---- S^T[key][q] = K · Q^T ----
        f4v sc[4][2] = {};
        #pragma unroll
        for (int kk = 0; kk < 2; ++kk) {
            const int ko = kk * 32 + quad * 8;
            s8v kf[4];
            #pragma unroll
            for (int j = 0; j < 4; ++j)
                kf[j] = *(const s8v*)(KsB + (j * 16 + l16) * 72 + ko);
            #pragma unroll
            for (int j = 0; j < 4; ++j)
                #pragma unroll
                for (int mi = 0; mi < 2; ++mi)
                    sc[j][mi] = __builtin_amdgcn_mfma_f32_16x16x32_bf16(
                        kf[j], qf[mi][kk], sc[j][mi], 0, 0, 0);
        }

        // ---- p = exp(s/8), pack to bf16, accumulate ROUNDED p into lsum ----
        #pragma unroll
        for (int j = 0; j < 4; ++j)
            #pragma unroll
            for (int mi = 0; mi < 2; ++mi) {
                const float p0 = __expf(sc[j][mi][0] * 0.125f);
                const float p1 = __expf(sc[j][mi][1] * 0.125f);
                const float p2 = __expf(sc[j][mi][2] * 0.125f);
                const float p3 = __expf(sc[j][mi][3] * 0.125f);
                union { unsigned u[2]; s4v s; } pv;
                pv.u[0] = pk2(p0, p1);
                pv.u[1] = pk2(p2, p3);
                lsum[mi] += (b2f_lo(pv.u[0]) + b2f_hi(pv.u[0]))
                          + (b2f_lo(pv.u[1]) + b2f_hi(pv.u[1]));
                *(s4v*)(Pt + (wave * 32 + mi * 16 + l16) * 72 + j * 16 + quad * 4) = pv.s;
            }

        // ---- O^T[d][q] += V^T[d][key] · P^T: A=Vs rows, B=Pt rows ----
        #pragma unroll
        for (int kk = 0; kk < 2; ++kk) {
            const int ko = kk * 32 + quad * 8;
            s8v pf[2];
            #pragma unroll
            for (int mi = 0; mi < 2; ++mi)
                pf[mi] = *(const s8v*)(Pt + (wave * 32 + mi * 16 + l16) * 72 + ko);
            #pragma unroll
            for (int j = 0; j < 4; ++j) {
                const s8v vf = *(const s8v*)(VsB + (j * 16 + l16) * 72 + ko);
                #pragma unroll
                for (int mi = 0; mi < 2; ++mi)
                    oacc[j][mi] = __builtin_amdgcn_mfma_f32_16x16x32_bf16(
                        vf, pf[mi], oacc[j][mi], 0, 0, 0);
            }
        }
    }

    // ---- full row sums: butterfly across quads (lane bits 4,5) ----
    #pragma unroll
    for (int mi = 0; mi < 2; ++mi) {
        float s = lsum[mi];
        s += __shfl_xor(s, 16);
        s += __shfl_xor(s, 32);
        lsum[mi] = 1.0f / s;
    }

    // ---- O^T C-layout -> LDS [q][d] packed (reuse Pt; wave-private) ----
    #pragma unroll
    for (int j = 0; j < 4; ++j)
        #pragma unroll
        for (int mi = 0; mi < 2; ++mi) {
            union { unsigned u[2]; s4v s; } ov;
            ov.u[0] = pk2(oacc[j][mi][0] * lsum[mi], oacc[j][mi][1] * lsum[mi]);
            ov.u[1] = pk2(oacc[j][mi][2] * lsum[mi], oacc[j][mi][3] * lsum[mi]);
            *(s4v*)(Pt + (wave * 32 + mi * 16 + l16) * 72 + j * 16 + quad * 4) = ov.s;
        }

    // ---- coalesced store, chunk-swizzled within the head's 128B group ----
    const int row = tid >> 1;
    const int cb  = (tid & 1) * 4;       // logical chunk base (0 or 4)
    #pragma unroll
    for (int c4 = 0; c4 < 4; ++c4) {
        const int lc = cb + c4;          // logical chunk 0..7
        const s8v t = *(const s8v*)(Pt + row * 72 + lc * 8);
        *(s8v*)(O + (size_t)(b * SEQ + q0 + row) * EMB + h * DHEAD
                  + ((lc ^ (row & 7)) * 8)) = t;
    }
}

extern "C" void kernel_launch(void* const* d_in, const int* in_sizes, int n_in,
                              void* d_out, int out_size, void* d_ws, size_t ws_size,
                              hipStream_t stream)
{
    const float* x  = (const float*)d_in[0];
    const float* Wq = (const float*)d_in[1];
    const float* bq = (const float*)d_in[2];
    const float* Wk = (const float*)d_in[3];
    const float* bk = (const float*)d_in[4];
    const float* Wv = (const float*)d_in[5];
    const float* bv = (const float*)d_in[6];
    const float* Wo = (const float*)d_in[7];
    const float* bo = (const float*)d_in[8];
    float* out = (float*)d_out;   // fp32 output

    short* xb  = (short*)d_ws;                       // 4096x1024 bf16, swizzled
    short* Wqb = xb  + (size_t)MTOT * EMB;           // swizzled
    short* Wkb = Wqb + (size_t)EMB * EMB;
    short* Wvb = Wkb + (size_t)EMB * EMB;
    short* Wob = Wvb + (size_t)EMB * EMB;
    short* Qw  = Wob + (size_t)EMB * EMB;            // [token][1024] (Q: plain;
                                                     //  then O: swizzled)
    short* Kw  = Qw  + (size_t)MTOT * EMB;           // [token][1024] plain
    short* Vtw = Kw  + (size_t)MTOT * EMB;           // [b][h][d][s] plain

    cvt_swz<<<dim3(512, 5), 256, 0, stream>>>(x, Wq, Wk, Wv, Wo,
                                              xb, Wqb, Wkb, Wvb, Wob);

    gemm_bb3<128, true><<<dim3(24, 32), 256, 0, stream>>>(
        xb, Wqb, Wkb, Wvb, bq, bk, bv, Qw, Kw, Vtw);

    attn_mfma4<<<dim3(BATCH * NHEAD * (SEQ / QT)), 256, 0, stream>>>(Qw, Kw, Vtw, Qw);

    gemm_bb3<64, false><<<dim3(16, 32), 256, 0, stream>>>(
        Qw, Wob, Wob, Wob, bo, bo, bo, out, out, out);
}